// Round 3
// baseline (121.640 us; speedup 1.0000x reference)
//
#include <hip/hip_runtime.h>
#include <math.h>

// ActELoss, symmetric reformulation, single fused kernel.
// S = sum_{b,i,j=0..10} exp(-|a0[i]-p0[i+j]|/2)*|a2[i]-p2[i+j]|, p = pad(6 first,5 last)
// Symmetry f(i,m)=f(m,i), f(i,i)=0:
//   S = 2*sum_{k=1..4} sum_i f(i,i+k) + sum_{k=5,6} sum_i f(i,i+k)
//     + sum_{i=1..5}(6-i) f(i,0) + sum_{i=746..748}(i-745) f(i,749)
// plus 0.1 * sum_b ||a0-a2||_2.  Per-block atomicAdd into d_out[0].

#define T_LEN 750
#define BLK   256
#define CPT   3            // positions per thread; 250 active threads
#define NACT  (T_LEN / CPT)
#define SPAD  756          // staged length: need reads up to i0+8 = 755
#define L2E_HALF 0.72134752044f   // 0.5 * log2(e)

__global__ __launch_bounds__(BLK) void actloss_fused(
    const float* __restrict__ a0, const float* __restrict__ a2,
    float* __restrict__ out)
{
    __shared__ float s0[SPAD];
    __shared__ float s2[SPAD];

    const int b   = blockIdx.x;
    const int tid = threadIdx.x;
    const float* __restrict__ g0 = a0 + (size_t)b * T_LEN;
    const float* __restrict__ g2 = a2 + (size_t)b * T_LEN;

    // Stage rows as float2 (rows are 8B-aligned: b*750*4 % 8 == 0).
    // 375 float2 per array; threads 0..374 handle one each (wraps once).
    {
        const float2* __restrict__ v0 = (const float2*)g0;
        const float2* __restrict__ v2 = (const float2*)g2;
        for (int k = tid; k < 375; k += BLK) {
            const float2 x0 = v0[k];
            const float2 x2 = v2[k];
            s0[2 * k]     = x0.x;
            s0[2 * k + 1] = x0.y;
            s2[2 * k]     = x2.x;
            s2[2 * k + 1] = x2.y;
        }
        // tail pad [750..755]: replicate last element (values masked anyway)
        if (tid < SPAD - T_LEN) {
            s0[T_LEN + tid] = g0[T_LEN - 1];
            s2[T_LEN + tid] = g2[T_LEN - 1];
        }
    }
    __syncthreads();

    float loss1 = 0.0f;   // weight-1 terms (k=5,6 and edge extras)
    float loss2 = 0.0f;   // weight-2 terms (k=1..4)
    float sq    = 0.0f;

    if (tid < NACT) {
        const int i0 = tid * CPT;
        float r0[CPT + 6], r2[CPT + 6];
#pragma unroll
        for (int k = 0; k < CPT + 6; ++k) {
            r0[k] = s0[i0 + k];
            r2[k] = s2[i0 + k];
        }
#pragma unroll
        for (int ci = 0; ci < CPT; ++ci) {
            const float c0 = r0[ci];
            const float c2 = r2[ci];
#pragma unroll
            for (int k = 1; k <= 6; ++k) {
                const float wv  = __builtin_amdgcn_exp2f(
                                      -L2E_HALF * fabsf(c0 - r0[ci + k]));
                float ad2 = fabsf(c2 - r2[ci + k]);
                ad2 = (i0 + ci + k < T_LEN) ? ad2 : 0.0f;   // drop out-of-range pairs
                if (k <= 4) loss2 = fmaf(wv, ad2, loss2);
                else        loss1 = fmaf(wv, ad2, loss1);
            }
            const float d = c0 - c2;
            sq = fmaf(d, d, sq);
        }
    } else if (tid == NACT) {
        // clamp edge extras (8 terms)
#pragma unroll
        for (int i = 1; i <= 5; ++i) {
            const float wv = __builtin_amdgcn_exp2f(-L2E_HALF * fabsf(s0[i] - s0[0]));
            loss1 = fmaf(wv * (float)(6 - i), fabsf(s2[i] - s2[0]), loss1);
        }
#pragma unroll
        for (int i = 746; i <= 748; ++i) {
            const float wv = __builtin_amdgcn_exp2f(-L2E_HALF * fabsf(s0[i] - s0[T_LEN - 1]));
            loss1 = fmaf(wv * (float)(i - 745), fabsf(s2[i] - s2[T_LEN - 1]), loss1);
        }
    }

    float loss = fmaf(2.0f, loss2, loss1);

    // wave64 shuffle reduce
#pragma unroll
    for (int off = 32; off > 0; off >>= 1) {
        loss += __shfl_down(loss, off, 64);
        sq   += __shfl_down(sq,   off, 64);
    }
    __shared__ float rl[BLK / 64], rs[BLK / 64];
    const int wid  = tid >> 6;
    const int lane = tid & 63;
    if (lane == 0) { rl[wid] = loss; rs[wid] = sq; }
    __syncthreads();
    if (tid == 0) {
        float L = 0.0f, S = 0.0f;
#pragma unroll
        for (int w = 0; w < BLK / 64; ++w) { L += rl[w]; S += rs[w]; }
        atomicAdd(out, L + 0.1f * sqrtf(S));   // device-scope by default
    }
}

extern "C" void kernel_launch(void* const* d_in, const int* in_sizes, int n_in,
                              void* d_out, int out_size, void* d_ws, size_t ws_size,
                              hipStream_t stream)
{
    const float* a0 = (const float*)d_in[0];
    const float* a2 = (const float*)d_in[1];
    float* out      = (float*)d_out;
    const int B = in_sizes[0] / T_LEN;           // 4096

    hipMemsetAsync(out, 0, sizeof(float), stream);   // d_out is poisoned 0xAA
    actloss_fused<<<B, BLK, 0, stream>>>(a0, a2, out);
}

// Round 4
// 74.553 us; speedup vs baseline: 1.6316x; 1.6316x over previous
//
#include <hip/hip_runtime.h>
#include <math.h>

// ActELoss, symmetric reformulation, two-kernel (atomic-free) reduction.
// S = sum_{b,i,j=0..10} exp(-|a0[i]-p0[i+j]|/2)*|a2[i]-p2[i+j]|, p = pad(6 first,5 last)
// Symmetry f(i,m)=f(m,i), f(i,i)=0:
//   S = 2*sum_{k=1..4} sum_i f(i,i+k) + sum_{k=5,6} sum_i f(i,i+k)
//     + sum_{i=1..5}(6-i) f(i,0) + sum_{i=746..748}(i-745) f(i,749)
// plus 0.1 * sum_b ||a0-a2||_2.
// NOTE (R3 lesson): same-address atomicAdd costs ~12 ns serialized on gfx950;
// 4096 of them = ~50 us tail. Partials + tiny second kernel is ~10x cheaper.

#define T_LEN 750
#define BLK   256
#define CPT   3            // positions per thread; 250 active threads
#define NACT  (T_LEN / CPT)
#define SPAD  756          // staged length: need reads up to i0+8 = 755
#define L2E_HALF 0.72134752044f   // 0.5 * log2(e)

__global__ __launch_bounds__(BLK) void actloss_partial(
    const float* __restrict__ a0, const float* __restrict__ a2,
    float* __restrict__ partials)
{
    __shared__ float s0[SPAD];
    __shared__ float s2[SPAD];

    const int b   = blockIdx.x;
    const int tid = threadIdx.x;
    const float* __restrict__ g0 = a0 + (size_t)b * T_LEN;
    const float* __restrict__ g2 = a2 + (size_t)b * T_LEN;

    // Stage rows as float2 (rows are 8B-aligned: b*750*4 % 8 == 0).
    {
        const float2* __restrict__ v0 = (const float2*)g0;
        const float2* __restrict__ v2 = (const float2*)g2;
        for (int k = tid; k < 375; k += BLK) {
            const float2 x0 = v0[k];
            const float2 x2 = v2[k];
            s0[2 * k]     = x0.x;
            s0[2 * k + 1] = x0.y;
            s2[2 * k]     = x2.x;
            s2[2 * k + 1] = x2.y;
        }
        // tail pad [750..755]: replicate last element (contributions masked)
        if (tid < SPAD - T_LEN) {
            s0[T_LEN + tid] = g0[T_LEN - 1];
            s2[T_LEN + tid] = g2[T_LEN - 1];
        }
    }
    __syncthreads();

    float loss1 = 0.0f;   // weight-1 terms (k=5,6 and edge extras)
    float loss2 = 0.0f;   // weight-2 terms (k=1..4)
    float sq    = 0.0f;

    if (tid < NACT) {
        const int i0 = tid * CPT;
        float r0[CPT + 6], r2[CPT + 6];
#pragma unroll
        for (int k = 0; k < CPT + 6; ++k) {
            r0[k] = s0[i0 + k];
            r2[k] = s2[i0 + k];
        }
#pragma unroll
        for (int ci = 0; ci < CPT; ++ci) {
            const float c0 = r0[ci];
            const float c2 = r2[ci];
#pragma unroll
            for (int k = 1; k <= 6; ++k) {
                const float wv  = __builtin_amdgcn_exp2f(
                                      -L2E_HALF * fabsf(c0 - r0[ci + k]));
                float ad2 = fabsf(c2 - r2[ci + k]);
                ad2 = (i0 + ci + k < T_LEN) ? ad2 : 0.0f;   // drop out-of-range pairs
                if (k <= 4) loss2 = fmaf(wv, ad2, loss2);
                else        loss1 = fmaf(wv, ad2, loss1);
            }
            const float d = c0 - c2;
            sq = fmaf(d, d, sq);
        }
    } else if (tid == NACT) {
        // clamp edge extras (8 terms)
#pragma unroll
        for (int i = 1; i <= 5; ++i) {
            const float wv = __builtin_amdgcn_exp2f(-L2E_HALF * fabsf(s0[i] - s0[0]));
            loss1 = fmaf(wv * (float)(6 - i), fabsf(s2[i] - s2[0]), loss1);
        }
#pragma unroll
        for (int i = 746; i <= 748; ++i) {
            const float wv = __builtin_amdgcn_exp2f(-L2E_HALF * fabsf(s0[i] - s0[T_LEN - 1]));
            loss1 = fmaf(wv * (float)(i - 745), fabsf(s2[i] - s2[T_LEN - 1]), loss1);
        }
    }

    float loss = fmaf(2.0f, loss2, loss1);

    // wave64 shuffle reduce
#pragma unroll
    for (int off = 32; off > 0; off >>= 1) {
        loss += __shfl_down(loss, off, 64);
        sq   += __shfl_down(sq,   off, 64);
    }
    __shared__ float rl[BLK / 64], rs[BLK / 64];
    const int wid  = tid >> 6;
    const int lane = tid & 63;
    if (lane == 0) { rl[wid] = loss; rs[wid] = sq; }
    __syncthreads();
    if (tid == 0) {
        float L = 0.0f, S = 0.0f;
#pragma unroll
        for (int w = 0; w < BLK / 64; ++w) { L += rl[w]; S += rs[w]; }
        partials[b] = L + 0.1f * sqrtf(S);
    }
}

__global__ __launch_bounds__(BLK) void actloss_final(
    const float* __restrict__ partials, int n4, float* __restrict__ out)
{
    // n4 = number of float4s (B/4 = 1024); 4 per thread, coalesced.
    const float4* __restrict__ p4 = (const float4*)partials;
    float v = 0.0f;
    for (int k = threadIdx.x; k < n4; k += BLK) {
        const float4 x = p4[k];
        v += (x.x + x.y) + (x.z + x.w);
    }
#pragma unroll
    for (int off = 32; off > 0; off >>= 1) v += __shfl_down(v, off, 64);
    __shared__ float r[BLK / 64];
    if ((threadIdx.x & 63) == 0) r[threadIdx.x >> 6] = v;
    __syncthreads();
    if (threadIdx.x == 0) {
        float s = 0.0f;
#pragma unroll
        for (int w = 0; w < BLK / 64; ++w) s += r[w];
        out[0] = s;
    }
}

extern "C" void kernel_launch(void* const* d_in, const int* in_sizes, int n_in,
                              void* d_out, int out_size, void* d_ws, size_t ws_size,
                              hipStream_t stream)
{
    const float* a0 = (const float*)d_in[0];
    const float* a2 = (const float*)d_in[1];
    float* out      = (float*)d_out;
    float* partials = (float*)d_ws;              // B floats, fully overwritten
    const int B = in_sizes[0] / T_LEN;           // 4096

    actloss_partial<<<B, BLK, 0, stream>>>(a0, a2, partials);
    actloss_final<<<1, BLK, 0, stream>>>(partials, B / 4, out);
}